// Round 4
// baseline (3196.702 us; speedup 1.0000x reference)
//
#include <hip/hip_runtime.h>
#include <hip/hip_bf16.h>

// Problem dims
#define T_DIM 256
#define B_DIM 64
#define I_DIM 512
#define H_DIM 1024
#define U_DIM 8
#define BN_EPS 1e-5f
#define NBLK 64   // blocks in persistent scan kernel
#define BH (B_DIM * H_DIM)

typedef __bf16 bf16x8 __attribute__((ext_vector_type(8)));
typedef float f32x4 __attribute__((ext_vector_type(4)));
typedef unsigned short u16;
typedef u16 u16x4 __attribute__((ext_vector_type(4)));
typedef unsigned long long u64;
typedef u64 u64x2 __attribute__((ext_vector_type(2)));
using bf16 = __hip_bfloat16;

// ---------------- conversion / packing kernels (vectorized) ----------------

__global__ void k_cvt4(const float* __restrict__ in, u16* __restrict__ out, int n4) {
    int i = blockIdx.x * blockDim.x + threadIdx.x;
    int stride = gridDim.x * blockDim.x;
    for (; i < n4; i += stride) {
        f32x4 v = *reinterpret_cast<const f32x4*>(in + (size_t)i * 4);
        u16x4 o;
#pragma unroll
        for (int j = 0; j < 4; ++j)
            o[j] = __bfloat16_as_ushort(__float2bfloat16(v[j]));
        *reinterpret_cast<u16x4*>(out + (size_t)i * 4) = o;
    }
}

// pack [Uz; Uh] into one [2048,1024] bf16 K-major matrix (4-elem chunks)
__global__ void k_pack_uzuh(const float* __restrict__ Uz, const float* __restrict__ Uh,
                            u16* __restrict__ out) {
    int i = blockIdx.x * 256 + threadIdx.x;
    int stride = gridDim.x * 256;
    int n4 = 2 * H_DIM * H_DIM / 4;
    for (; i < n4; i += stride) {
        int c = i * 4;
        int n = c >> 10, k = c & 1023;
        const float* src = (n < H_DIM) ? (Uz + (size_t)n * H_DIM + k)
                                       : (Uh + (size_t)(n - H_DIM) * H_DIM + k);
        f32x4 v = *reinterpret_cast<const f32x4*>(src);
        u16x4 o;
#pragma unroll
        for (int j = 0; j < 4; ++j)
            o[j] = __bfloat16_as_ushort(__float2bfloat16(v[j]));
        *reinterpret_cast<u16x4*>(out + c) = o;
    }
}

// extract block-diagonal of Wm = Wh_in * mask: wdiag[h*8+u] = Wm[h][h*8+u]
__global__ void k_wdiag(const float* __restrict__ Wh_in, const float* __restrict__ mask,
                        float* __restrict__ wdiag) {
    int idx = blockIdx.x * 256 + threadIdx.x;
    if (idx < H_DIM * U_DIM) {
        int h = idx >> 3;
        size_t col = (size_t)h * (H_DIM * U_DIM) + idx;
        wdiag[idx] = Wh_in[col] * mask[col];
    }
}

// ---------------- GEMM+BN fused: bnz = BN(x @ Wzx.T) (bf16), T-tiled x4 ----------------
// grid (H/64, T/4), 256 threads = 4 waves (wave = m-quarter). B-frags reused across 4 t.

__global__ __launch_bounds__(256) void k_gemm_zx(const bf16* __restrict__ xb,
                                                 const bf16* __restrict__ wzx,
                                                 const float* __restrict__ g,
                                                 const float* __restrict__ bta,
                                                 bf16* __restrict__ bnz) {
    int t0 = blockIdx.y * 4;
    int h0 = blockIdx.x * 64;
    int lane = threadIdx.x & 63;
    int wid = threadIdx.x >> 6;
    int r15 = lane & 15;
    int kseg = lane >> 4;
    const bf16* xbase = xb + (size_t)(t0 * B_DIM + wid * 16 + r15) * I_DIM + kseg * 8;
    f32x4 acc[4][4] = {};  // [tt][nf]
    for (int kk = 0; kk < I_DIM; kk += 32) {
        bf16x8 b[4];
#pragma unroll
        for (int nf = 0; nf < 4; ++nf)
            b[nf] = *reinterpret_cast<const bf16x8*>(
                wzx + (size_t)(h0 + nf * 16 + r15) * I_DIM + kk + kseg * 8);
#pragma unroll
        for (int tt = 0; tt < 4; ++tt) {
            bf16x8 a = *reinterpret_cast<const bf16x8*>(xbase + (size_t)tt * B_DIM * I_DIM + kk);
#pragma unroll
            for (int nf = 0; nf < 4; ++nf)
                acc[tt][nf] = __builtin_amdgcn_mfma_f32_16x16x32_bf16(a, b[nf], acc[tt][nf], 0, 0, 0);
        }
    }
    // ---- fused BN (per tt) ----
    __shared__ float sB[2][4][4][64];  // [stat][wid][tt][col]
#pragma unroll
    for (int tt = 0; tt < 4; ++tt)
#pragma unroll
        for (int nf = 0; nf < 4; ++nf) {
            float s = acc[tt][nf][0] + acc[tt][nf][1] + acc[tt][nf][2] + acc[tt][nf][3];
            float s2 = acc[tt][nf][0] * acc[tt][nf][0] + acc[tt][nf][1] * acc[tt][nf][1] +
                       acc[tt][nf][2] * acc[tt][nf][2] + acc[tt][nf][3] * acc[tt][nf][3];
            s += __shfl_xor(s, 16);  s += __shfl_xor(s, 32);
            s2 += __shfl_xor(s2, 16); s2 += __shfl_xor(s2, 32);
            if (lane < 16) {
                sB[0][wid][tt][nf * 16 + r15] = s;
                sB[1][wid][tt][nf * 16 + r15] = s2;
            }
        }
    __syncthreads();
    int bb = wid * 16 + kseg * 4;
#pragma unroll
    for (int tt = 0; tt < 4; ++tt)
#pragma unroll
        for (int nf = 0; nf < 4; ++nf) {
            int c = nf * 16 + r15;
            float s = sB[0][0][tt][c] + sB[0][1][tt][c] + sB[0][2][tt][c] + sB[0][3][tt][c];
            float s2 = sB[1][0][tt][c] + sB[1][1][tt][c] + sB[1][2][tt][c] + sB[1][3][tt][c];
            float mu = s * (1.f / B_DIM);
            float var = s2 * (1.f / B_DIM) - mu * mu;
            int h = h0 + c;
            float sc = rsqrtf(var + BN_EPS) * g[h];
            float sh = bta[h] - mu * sc;
#pragma unroll
            for (int j = 0; j < 4; ++j)
                bnz[(size_t)((t0 + tt) * B_DIM + bb + j) * H_DIM + h] =
                    __float2bfloat16(acc[tt][nf][j] * sc + sh);
        }
}

// ---- GEMM+BN fused: bnh = BN(relu(x @ Whx.T + b_unit) @ Wm.T) (bf16), T-tiled x4 ----
// grid (H/16, T/4): block = [64 x 128] u-tile x 4 timesteps

__global__ __launch_bounds__(256) void k_gemm_s(const bf16* __restrict__ xb,
                                                const bf16* __restrict__ whx,
                                                const float* __restrict__ b_unit,
                                                const float* __restrict__ wdiag,
                                                const float* __restrict__ g,
                                                const float* __restrict__ bta,
                                                bf16* __restrict__ bnh) {
    int t0 = blockIdx.y * 4;
    int h0 = blockIdx.x * 16;
    int u0 = h0 * U_DIM;
    int lane = threadIdx.x & 63;
    int wid = threadIdx.x >> 6;
    int r15 = lane & 15;
    int kseg = lane >> 4;
    const bf16* xbase = xb + (size_t)(t0 * B_DIM + wid * 16 + r15) * I_DIM + kseg * 8;
    f32x4 acc[4][8] = {};  // [tt][nf]
    for (int kk = 0; kk < I_DIM; kk += 32) {
        bf16x8 b[8];
#pragma unroll
        for (int nf = 0; nf < 8; ++nf)
            b[nf] = *reinterpret_cast<const bf16x8*>(
                whx + (size_t)(u0 + nf * 16 + r15) * I_DIM + kk + kseg * 8);
#pragma unroll
        for (int tt = 0; tt < 4; ++tt) {
            bf16x8 a = *reinterpret_cast<const bf16x8*>(xbase + (size_t)tt * B_DIM * I_DIM + kk);
#pragma unroll
            for (int nf = 0; nf < 8; ++nf)
                acc[tt][nf] = __builtin_amdgcn_mfma_f32_16x16x32_bf16(a, b[nf], acc[tt][nf], 0, 0, 0);
        }
    }
    // relu+bias+scale, reduce u-groups of 8 lanes
    int uloc = r15 & 7;
#pragma unroll
    for (int nf = 0; nf < 8; ++nf) {
        int ucol = u0 + nf * 16 + r15;
        float wd = wdiag[ucol];
        float bu = b_unit[ucol];
#pragma unroll
        for (int tt = 0; tt < 4; ++tt)
#pragma unroll
            for (int j = 0; j < 4; ++j) {
                float v = fmaxf(acc[tt][nf][j] + bu, 0.f) * wd;
                v += __shfl_xor(v, 1);
                v += __shfl_xor(v, 2);
                v += __shfl_xor(v, 4);
                acc[tt][nf][j] = v;
            }
    }
    // ---- fused BN over batch for 16 h cols x 4 tt ----
    __shared__ float sS[2][4][4][16];  // [stat][wid][tt][c]
#pragma unroll
    for (int tt = 0; tt < 4; ++tt)
#pragma unroll
        for (int nf = 0; nf < 8; ++nf) {
            float s = 0.f, s2 = 0.f;
            if (uloc == 0) {
#pragma unroll
                for (int j = 0; j < 4; ++j) { s += acc[tt][nf][j]; s2 += acc[tt][nf][j] * acc[tt][nf][j]; }
            }
            s += __shfl_xor(s, 16);  s += __shfl_xor(s, 32);
            s2 += __shfl_xor(s2, 16); s2 += __shfl_xor(s2, 32);
            if (lane == 0 || lane == 8) {
                int c = nf * 2 + (r15 >> 3);
                sS[0][wid][tt][c] = s;
                sS[1][wid][tt][c] = s2;
            }
        }
    __syncthreads();
    int bb = wid * 16 + kseg * 4;
#pragma unroll
    for (int tt = 0; tt < 4; ++tt)
#pragma unroll
        for (int nf = 0; nf < 8; ++nf) {
            int c = nf * 2 + (r15 >> 3);
            float s = sS[0][0][tt][c] + sS[0][1][tt][c] + sS[0][2][tt][c] + sS[0][3][tt][c];
            float s2 = sS[1][0][tt][c] + sS[1][1][tt][c] + sS[1][2][tt][c] + sS[1][3][tt][c];
            float mu = s * (1.f / B_DIM);
            float var = s2 * (1.f / B_DIM) - mu * mu;
            int h = h0 + c;
            float sc = rsqrtf(var + BN_EPS) * g[h];
            float sh = bta[h] - mu * sc;
            if (uloc == 0) {
#pragma unroll
                for (int j = 0; j < 4; ++j)
                    bnh[(size_t)((t0 + tt) * B_DIM + bb + j) * H_DIM + h] =
                        __float2bfloat16(acc[tt][nf][j] * sc + sh);
            }
        }
}

// ---------------- persistent scan kernel (fence-free, operand-swapped) ----------------
// 64 blocks x 512 threads. Block owns 16 h-cols. Wave w: mq=w&3 (batch tile),
// kq=w>>2 (k-half). Computes D = U . h^T: A-frag = U rows (registers, static),
// B-frag = h rows (coherent relaxed-atomic u64 loads, no fences). D lane map:
// col = lane&15 = batch(local), rows = (lane>>4)*4+j = 4 consecutive h-dims ->
// h store is one contiguous u64 atomic; out is one contiguous f32x4 plain store.

__global__ __launch_bounds__(512, 2) void k_scan(const bf16* __restrict__ uzuh,
                                                 const bf16* __restrict__ bnz,
                                                 const bf16* __restrict__ bnh,
                                                 bf16* __restrict__ hb0,
                                                 bf16* __restrict__ hb1,
                                                 float* __restrict__ out,
                                                 unsigned* __restrict__ flags) {
    int tid = threadIdx.x;
    int lane = tid & 63, w = tid >> 6;
    int mq = w & 3, kq = w >> 2;
    int r15 = lane & 15, kseg = lane >> 4;
    int h0 = blockIdx.x * 16;

    // permanent A fragments: U rows = this block's h-cols, this wave's k-half
    bf16x8 aZ[16], aH[16];
    {
        const bf16* azb = uzuh + (size_t)(h0 + r15) * H_DIM + kq * 512 + kseg * 8;
        const bf16* ahb = azb + (size_t)H_DIM * H_DIM;
#pragma unroll
        for (int i = 0; i < 16; ++i) {
            aZ[i] = *reinterpret_cast<const bf16x8*>(azb + i * 32);
            aH[i] = *reinterpret_cast<const bf16x8*>(ahb + i * 32);
        }
    }

    __shared__ float red[2][4][64][4];  // [Z|H][mq][lane][j] partials from kq==1

    int batch = mq * 16 + r15;          // h row for B-frag loads AND C-frag col
    int hd0 = h0 + kseg * 4;            // first of this lane's 4 h-dims (C rows)

    f32x4 hreg = {};                    // fp32 h state: (batch, hd0..hd0+3)
    float bzv[4], bhv[4];
    if (kq == 0) {
        u16x4 vz = *reinterpret_cast<const u16x4*>(bnz + (size_t)batch * H_DIM + hd0);
        u16x4 vh = *reinterpret_cast<const u16x4*>(bnh + (size_t)batch * H_DIM + hd0);
#pragma unroll
        for (int j = 0; j < 4; ++j) {
            bzv[j] = __bfloat162float(__ushort_as_bfloat16(vz[j]));
            bhv[j] = __bfloat162float(__ushort_as_bfloat16(vh[j]));
        }
    }

    for (int t = 0; t < T_DIM; ++t) {
        const bf16* hbc = (t & 1) ? hb1 : hb0;
        bf16* hbn = (t & 1) ? hb0 : hb1;

        // B-frag = h_prev rows via coherent relaxed atomics (u64 x2 per 16B)
        f32x4 accZ = {}, accH = {};
        u64* hp = (u64*)(hbc + (size_t)batch * H_DIM + kq * 512 + kseg * 8);
#pragma unroll
        for (int i = 0; i < 16; ++i) {
            u64 lo = __hip_atomic_load(hp + i * 8, __ATOMIC_RELAXED, __HIP_MEMORY_SCOPE_AGENT);
            u64 hi = __hip_atomic_load(hp + i * 8 + 1, __ATOMIC_RELAXED, __HIP_MEMORY_SCOPE_AGENT);
            u64x2 q; q[0] = lo; q[1] = hi;
            bf16x8 b = __builtin_bit_cast(bf16x8, q);
            accZ = __builtin_amdgcn_mfma_f32_16x16x32_bf16(aZ[i], b, accZ, 0, 0, 0);
            accH = __builtin_amdgcn_mfma_f32_16x16x32_bf16(aH[i], b, accH, 0, 0, 0);
        }

        if (kq == 1) {
            *reinterpret_cast<f32x4*>(&red[0][mq][lane][0]) = accZ;
            *reinterpret_cast<f32x4*>(&red[1][mq][lane][0]) = accH;
        }
        __syncthreads();

        if (kq == 0) {
            accZ += *reinterpret_cast<const f32x4*>(&red[0][mq][lane][0]);
            accH += *reinterpret_cast<const f32x4*>(&red[1][mq][lane][0]);
#pragma unroll
            for (int j = 0; j < 4; ++j) {
                float z = 1.f / (1.f + expf(-(bzv[j] + accZ[j])));
                float hu = fmaxf(bhv[j] + accH[j], 0.f);
                hreg[j] = z * hreg[j] + (1.f - z) * hu;
            }
            // contiguous stores: fp32 out (plain), bf16 h (coherent atomic u64)
            *reinterpret_cast<f32x4*>(out + (size_t)t * BH + (size_t)batch * H_DIM + hd0) = hreg;
            u16x4 o;
#pragma unroll
            for (int j = 0; j < 4; ++j)
                o[j] = __bfloat16_as_ushort(__float2bfloat16(hreg[j]));
            __hip_atomic_store((u64*)(hbn + (size_t)batch * H_DIM + hd0),
                               __builtin_bit_cast(u64, o),
                               __ATOMIC_RELAXED, __HIP_MEMORY_SCOPE_AGENT);
            if (t == T_DIM - 1)
                *reinterpret_cast<f32x4*>(out + (size_t)T_DIM * BH + (size_t)batch * H_DIM + hd0) = hreg;
            // prefetch next step's BN'd projections (plain cached loads)
            if (t + 1 < T_DIM) {
                u16x4 vz = *reinterpret_cast<const u16x4*>(
                    bnz + (size_t)(t + 1) * BH + (size_t)batch * H_DIM + hd0);
                u16x4 vh = *reinterpret_cast<const u16x4*>(
                    bnh + (size_t)(t + 1) * BH + (size_t)batch * H_DIM + hd0);
#pragma unroll
                for (int j = 0; j < 4; ++j) {
                    bzv[j] = __bfloat162float(__ushort_as_bfloat16(vz[j]));
                    bhv[j] = __bfloat162float(__ushort_as_bfloat16(vh[j]));
                }
            }
        }

        if (t < T_DIM - 1) {
            __syncthreads();   // all waves' stores drained (vmcnt(0) before s_barrier)
            if (w == 0) {
                if (lane == 0)
                    __hip_atomic_store(&flags[(size_t)blockIdx.x * 16], (unsigned)(t + 1),
                                       __ATOMIC_RELAXED, __HIP_MEMORY_SCOPE_AGENT);
                unsigned v;
                do {
                    v = __hip_atomic_load(&flags[(size_t)lane * 16],
                                          __ATOMIC_RELAXED, __HIP_MEMORY_SCOPE_AGENT);
                    if (!__any(v <= (unsigned)t)) break;
                    __builtin_amdgcn_s_sleep(1);
                } while (true);
            }
            __syncthreads();
        }
    }
}

// ---------------- workspace layout (bytes) ----------------
#define OFF_XB    ((size_t)0)                     // 16 MB  bf16 x
#define OFF_WZX   ((size_t)16777216)              // 1 MB
#define OFF_WHX   ((size_t)17825792)              // 8 MB
#define OFF_UZUH  ((size_t)26214400)              // 4 MB
#define OFF_WDIAG ((size_t)30408704)              // 32 KB
#define OFF_BNZ   ((size_t)30441472)              // 32 MB
#define OFF_BNH   ((size_t)63995904)              // 32 MB
#define OFF_BAR   ((size_t)97550336)              // 4 KB flag array
#define OFF_HB0   ((size_t)98074624)              // 128 KB
#define OFF_HB1   ((size_t)98205696)              // 128 KB

extern "C" void kernel_launch(void* const* d_in, const int* in_sizes, int n_in,
                              void* d_out, int out_size, void* d_ws, size_t ws_size,
                              hipStream_t stream) {
    const float* x      = (const float*)d_in[0];
    const float* Wzx    = (const float*)d_in[1];
    const float* Whx    = (const float*)d_in[2];
    const float* Uz     = (const float*)d_in[3];
    const float* Uh     = (const float*)d_in[4];
    const float* b_unit = (const float*)d_in[5];
    const float* Wh_in  = (const float*)d_in[6];
    const float* gz     = (const float*)d_in[7];
    const float* bz     = (const float*)d_in[8];
    const float* gh     = (const float*)d_in[9];
    const float* bh     = (const float*)d_in[10];
    const float* mask   = (const float*)d_in[11];

    char* ws = (char*)d_ws;
    bf16*     xb    = (bf16*)(ws + OFF_XB);
    bf16*     wzx_b = (bf16*)(ws + OFF_WZX);
    bf16*     whx_b = (bf16*)(ws + OFF_WHX);
    bf16*     uzuh  = (bf16*)(ws + OFF_UZUH);
    float*    wdiag = (float*)(ws + OFF_WDIAG);
    bf16*     bnz   = (bf16*)(ws + OFF_BNZ);
    bf16*     bnh   = (bf16*)(ws + OFF_BNH);
    unsigned* flags = (unsigned*)(ws + OFF_BAR);
    bf16*     hb0   = (bf16*)(ws + OFF_HB0);
    bf16*     hb1   = (bf16*)(ws + OFF_HB1);

    float* out = (float*)d_out;

    // 1. convert inputs to bf16 (vectorized)
    k_cvt4<<<2048, 256, 0, stream>>>(x, (u16*)xb, T_DIM * B_DIM * I_DIM / 4);
    k_cvt4<<<512, 256, 0, stream>>>(Wzx, (u16*)wzx_b, H_DIM * I_DIM / 4);
    k_cvt4<<<2048, 256, 0, stream>>>(Whx, (u16*)whx_b, U_DIM * H_DIM * I_DIM / 4);
    k_pack_uzuh<<<2048, 256, 0, stream>>>(Uz, Uh, (u16*)uzuh);
    k_wdiag<<<(H_DIM * U_DIM + 255) / 256, 256, 0, stream>>>(Wh_in, mask, wdiag);

    // 2. fused GEMM+BN -> bnz, bnh (bf16), T-tiled x4
    {
        dim3 gz_grid(H_DIM / 64, T_DIM / 4);
        k_gemm_zx<<<gz_grid, 256, 0, stream>>>(xb, wzx_b, gz, bz, bnz);
        dim3 gs_grid(H_DIM / 16, T_DIM / 4);
        k_gemm_s<<<gs_grid, 256, 0, stream>>>(xb, whx_b, b_unit, wdiag, gh, bh, bnh);
    }

    // 3. init h = 0 and flags = 0
    hipMemsetAsync(hb0, 0, (size_t)BH * sizeof(bf16), stream);
    hipMemsetAsync(flags, 0, 4096, stream);

    // 4. persistent scan: fence-free, coherent-atomic h exchange
    k_scan<<<NBLK, 512, 0, stream>>>(uzuh, bnz, bnh, hb0, hb1, out, flags);
}

// Round 5
// 2505.153 us; speedup vs baseline: 1.2761x; 1.2761x over previous
//
#include <hip/hip_runtime.h>
#include <hip/hip_bf16.h>

// Problem dims
#define T_DIM 256
#define B_DIM 64
#define I_DIM 512
#define H_DIM 1024
#define U_DIM 8
#define BN_EPS 1e-5f
#define BH (B_DIM * H_DIM)

typedef __bf16 bf16x8 __attribute__((ext_vector_type(8)));
typedef float f32x4 __attribute__((ext_vector_type(4)));
typedef unsigned short u16;
typedef u16 u16x4 __attribute__((ext_vector_type(4)));
typedef unsigned long long u64;
using bf16 = __hip_bfloat16;

// ---------------- conversion / packing kernels (vectorized) ----------------

__global__ void k_cvt4(const float* __restrict__ in, u16* __restrict__ out, int n4) {
    int i = blockIdx.x * blockDim.x + threadIdx.x;
    int stride = gridDim.x * blockDim.x;
    for (; i < n4; i += stride) {
        f32x4 v = *reinterpret_cast<const f32x4*>(in + (size_t)i * 4);
        u16x4 o;
#pragma unroll
        for (int j = 0; j < 4; ++j)
            o[j] = __bfloat16_as_ushort(__float2bfloat16(v[j]));
        *reinterpret_cast<u16x4*>(out + (size_t)i * 4) = o;
    }
}

// pack [Uz; Uh] into one [2048,1024] bf16 K-major matrix (4-elem chunks)
__global__ void k_pack_uzuh(const float* __restrict__ Uz, const float* __restrict__ Uh,
                            u16* __restrict__ out) {
    int i = blockIdx.x * 256 + threadIdx.x;
    int stride = gridDim.x * 256;
    int n4 = 2 * H_DIM * H_DIM / 4;
    for (; i < n4; i += stride) {
        int c = i * 4;
        int n = c >> 10, k = c & 1023;
        const float* src = (n < H_DIM) ? (Uz + (size_t)n * H_DIM + k)
                                       : (Uh + (size_t)(n - H_DIM) * H_DIM + k);
        f32x4 v = *reinterpret_cast<const f32x4*>(src);
        u16x4 o;
#pragma unroll
        for (int j = 0; j < 4; ++j)
            o[j] = __bfloat16_as_ushort(__float2bfloat16(v[j]));
        *reinterpret_cast<u16x4*>(out + c) = o;
    }
}

// extract block-diagonal of Wm = Wh_in * mask: wdiag[h*8+u] = Wm[h][h*8+u]
__global__ void k_wdiag(const float* __restrict__ Wh_in, const float* __restrict__ mask,
                        float* __restrict__ wdiag) {
    int idx = blockIdx.x * 256 + threadIdx.x;
    if (idx < H_DIM * U_DIM) {
        int h = idx >> 3;
        size_t col = (size_t)h * (H_DIM * U_DIM) + idx;
        wdiag[idx] = Wh_in[col] * mask[col];
    }
}

// ---------------- GEMM+BN fused: bnz = BN(x @ Wzx.T) (bf16), T-tiled x4 ----------------

__global__ __launch_bounds__(256) void k_gemm_zx(const bf16* __restrict__ xb,
                                                 const bf16* __restrict__ wzx,
                                                 const float* __restrict__ g,
                                                 const float* __restrict__ bta,
                                                 bf16* __restrict__ bnz) {
    int t0 = blockIdx.y * 4;
    int h0 = blockIdx.x * 64;
    int lane = threadIdx.x & 63;
    int wid = threadIdx.x >> 6;
    int r15 = lane & 15;
    int kseg = lane >> 4;
    const bf16* xbase = xb + (size_t)(t0 * B_DIM + wid * 16 + r15) * I_DIM + kseg * 8;
    f32x4 acc[4][4] = {};  // [tt][nf]
    for (int kk = 0; kk < I_DIM; kk += 32) {
        bf16x8 b[4];
#pragma unroll
        for (int nf = 0; nf < 4; ++nf)
            b[nf] = *reinterpret_cast<const bf16x8*>(
                wzx + (size_t)(h0 + nf * 16 + r15) * I_DIM + kk + kseg * 8);
#pragma unroll
        for (int tt = 0; tt < 4; ++tt) {
            bf16x8 a = *reinterpret_cast<const bf16x8*>(xbase + (size_t)tt * B_DIM * I_DIM + kk);
#pragma unroll
            for (int nf = 0; nf < 4; ++nf)
                acc[tt][nf] = __builtin_amdgcn_mfma_f32_16x16x32_bf16(a, b[nf], acc[tt][nf], 0, 0, 0);
        }
    }
    __shared__ float sB[2][4][4][64];  // [stat][wid][tt][col]
#pragma unroll
    for (int tt = 0; tt < 4; ++tt)
#pragma unroll
        for (int nf = 0; nf < 4; ++nf) {
            float s = acc[tt][nf][0] + acc[tt][nf][1] + acc[tt][nf][2] + acc[tt][nf][3];
            float s2 = acc[tt][nf][0] * acc[tt][nf][0] + acc[tt][nf][1] * acc[tt][nf][1] +
                       acc[tt][nf][2] * acc[tt][nf][2] + acc[tt][nf][3] * acc[tt][nf][3];
            s += __shfl_xor(s, 16);  s += __shfl_xor(s, 32);
            s2 += __shfl_xor(s2, 16); s2 += __shfl_xor(s2, 32);
            if (lane < 16) {
                sB[0][wid][tt][nf * 16 + r15] = s;
                sB[1][wid][tt][nf * 16 + r15] = s2;
            }
        }
    __syncthreads();
    int bb = wid * 16 + kseg * 4;
#pragma unroll
    for (int tt = 0; tt < 4; ++tt)
#pragma unroll
        for (int nf = 0; nf < 4; ++nf) {
            int c = nf * 16 + r15;
            float s = sB[0][0][tt][c] + sB[0][1][tt][c] + sB[0][2][tt][c] + sB[0][3][tt][c];
            float s2 = sB[1][0][tt][c] + sB[1][1][tt][c] + sB[1][2][tt][c] + sB[1][3][tt][c];
            float mu = s * (1.f / B_DIM);
            float var = s2 * (1.f / B_DIM) - mu * mu;
            int h = h0 + c;
            float sc = rsqrtf(var + BN_EPS) * g[h];
            float sh = bta[h] - mu * sc;
#pragma unroll
            for (int j = 0; j < 4; ++j)
                bnz[(size_t)((t0 + tt) * B_DIM + bb + j) * H_DIM + h] =
                    __float2bfloat16(acc[tt][nf][j] * sc + sh);
        }
}

// ---- GEMM+BN fused: bnh = BN(relu(x @ Whx.T + b_unit) @ Wm.T) (bf16), T-tiled x4 ----

__global__ __launch_bounds__(256) void k_gemm_s(const bf16* __restrict__ xb,
                                                const bf16* __restrict__ whx,
                                                const float* __restrict__ b_unit,
                                                const float* __restrict__ wdiag,
                                                const float* __restrict__ g,
                                                const float* __restrict__ bta,
                                                bf16* __restrict__ bnh) {
    int t0 = blockIdx.y * 4;
    int h0 = blockIdx.x * 16;
    int u0 = h0 * U_DIM;
    int lane = threadIdx.x & 63;
    int wid = threadIdx.x >> 6;
    int r15 = lane & 15;
    int kseg = lane >> 4;
    const bf16* xbase = xb + (size_t)(t0 * B_DIM + wid * 16 + r15) * I_DIM + kseg * 8;
    f32x4 acc[4][8] = {};  // [tt][nf]
    for (int kk = 0; kk < I_DIM; kk += 32) {
        bf16x8 b[8];
#pragma unroll
        for (int nf = 0; nf < 8; ++nf)
            b[nf] = *reinterpret_cast<const bf16x8*>(
                whx + (size_t)(u0 + nf * 16 + r15) * I_DIM + kk + kseg * 8);
#pragma unroll
        for (int tt = 0; tt < 4; ++tt) {
            bf16x8 a = *reinterpret_cast<const bf16x8*>(xbase + (size_t)tt * B_DIM * I_DIM + kk);
#pragma unroll
            for (int nf = 0; nf < 8; ++nf)
                acc[tt][nf] = __builtin_amdgcn_mfma_f32_16x16x32_bf16(a, b[nf], acc[tt][nf], 0, 0, 0);
        }
    }
    int uloc = r15 & 7;
#pragma unroll
    for (int nf = 0; nf < 8; ++nf) {
        int ucol = u0 + nf * 16 + r15;
        float wd = wdiag[ucol];
        float bu = b_unit[ucol];
#pragma unroll
        for (int tt = 0; tt < 4; ++tt)
#pragma unroll
            for (int j = 0; j < 4; ++j) {
                float v = fmaxf(acc[tt][nf][j] + bu, 0.f) * wd;
                v += __shfl_xor(v, 1);
                v += __shfl_xor(v, 2);
                v += __shfl_xor(v, 4);
                acc[tt][nf][j] = v;
            }
    }
    __shared__ float sS[2][4][4][16];  // [stat][wid][tt][c]
#pragma unroll
    for (int tt = 0; tt < 4; ++tt)
#pragma unroll
        for (int nf = 0; nf < 8; ++nf) {
            float s = 0.f, s2 = 0.f;
            if (uloc == 0) {
#pragma unroll
                for (int j = 0; j < 4; ++j) { s += acc[tt][nf][j]; s2 += acc[tt][nf][j] * acc[tt][nf][j]; }
            }
            s += __shfl_xor(s, 16);  s += __shfl_xor(s, 32);
            s2 += __shfl_xor(s2, 16); s2 += __shfl_xor(s2, 32);
            if (lane == 0 || lane == 8) {
                int c = nf * 2 + (r15 >> 3);
                sS[0][wid][tt][c] = s;
                sS[1][wid][tt][c] = s2;
            }
        }
    __syncthreads();
    int bb = wid * 16 + kseg * 4;
#pragma unroll
    for (int tt = 0; tt < 4; ++tt)
#pragma unroll
        for (int nf = 0; nf < 8; ++nf) {
            int c = nf * 2 + (r15 >> 3);
            float s = sS[0][0][tt][c] + sS[0][1][tt][c] + sS[0][2][tt][c] + sS[0][3][tt][c];
            float s2 = sS[1][0][tt][c] + sS[1][1][tt][c] + sS[1][2][tt][c] + sS[1][3][tt][c];
            float mu = s * (1.f / B_DIM);
            float var = s2 * (1.f / B_DIM) - mu * mu;
            int h = h0 + c;
            float sc = rsqrtf(var + BN_EPS) * g[h];
            float sh = bta[h] - mu * sc;
            if (uloc == 0) {
#pragma unroll
                for (int j = 0; j < 4; ++j)
                    bnh[(size_t)((t0 + tt) * B_DIM + bb + j) * H_DIM + h] =
                        __float2bfloat16(acc[tt][nf][j] * sc + sh);
            }
        }
}

// ---------------- persistent scan: 4 independent cohorts of 16 blocks ----------------
// Cohort c owns batch rows [16c,16c+16) — batch rows are independent (BN precomputed),
// so cohorts never synchronize with each other. Block (within cohort) owns 64 h-cols;
// 8 waves = 4 col-groups (cg) x 2 k-halves (kq). U frags permanent in registers.
// D = U . h^T (operand-swapped, validated R4): lane l -> batch col = l&15,
// h-dim rows = cg*16 + (l>>4)*4 + j  => contiguous h/out stores.
// Exchange: plain cached loads/stores + release-flag (L2 wb) / acquire-fence (L2 inv)
// per 16-party cohort barrier (scheme validated R3).

__global__ __launch_bounds__(512) void k_scan(const bf16* __restrict__ uzuh,
                                              const bf16* __restrict__ bnz,
                                              const bf16* __restrict__ bnh,
                                              bf16* __restrict__ hb0,
                                              bf16* __restrict__ hb1,
                                              float* __restrict__ out,
                                              unsigned* __restrict__ flags) {
    int tid = threadIdx.x;
    int lane = tid & 63, w = tid >> 6;
    int cg = w >> 1, kq = w & 1;
    int r15 = lane & 15, kseg = lane >> 4;
    int cohort = blockIdx.x & 3, blk = blockIdx.x >> 2;
    int h0 = blk * 64 + cg * 16;        // this wave's 16 U columns (h-dims)
    int batch = cohort * 16 + r15;      // B-frag row & (kq==0) C-frag col
    int hd0 = blk * 64 + cg * 16 + kseg * 4;  // kq==0 lane's first h-dim

    // permanent A fragments: U rows = this wave's 16 h-cols, its k-half
    bf16x8 aZ[16], aH[16];
    {
        const bf16* azb = uzuh + (size_t)(h0 + r15) * H_DIM + kq * 512 + kseg * 8;
        const bf16* ahb = azb + (size_t)H_DIM * H_DIM;
#pragma unroll
        for (int i = 0; i < 16; ++i) {
            aZ[i] = *reinterpret_cast<const bf16x8*>(azb + i * 32);
            aH[i] = *reinterpret_cast<const bf16x8*>(ahb + i * 32);
        }
    }

    __shared__ float red[2][4][64][4];  // [Z|H][cg][lane][j] partials from kq==1

    f32x4 hreg = {};                    // fp32 h state: (batch, hd0..hd0+3)
    float bzv[4], bhv[4];
    if (kq == 0) {
        u16x4 vz = *reinterpret_cast<const u16x4*>(bnz + (size_t)batch * H_DIM + hd0);
        u16x4 vh = *reinterpret_cast<const u16x4*>(bnh + (size_t)batch * H_DIM + hd0);
#pragma unroll
        for (int j = 0; j < 4; ++j) {
            bzv[j] = __bfloat162float(__ushort_as_bfloat16(vz[j]));
            bhv[j] = __bfloat162float(__ushort_as_bfloat16(vh[j]));
        }
    }

    for (int t = 0; t < T_DIM; ++t) {
        const bf16* hbc = (t & 1) ? hb1 : hb0;
        bf16* hbn = (t & 1) ? hb0 : hb1;

        // stage ALL 16 B-frags (h rows) first -> full memory-level parallelism
        bf16x8 hfrag[16];
        const bf16* hp = hbc + (size_t)batch * H_DIM + kq * 512 + kseg * 8;
#pragma unroll
        for (int i = 0; i < 16; ++i)
            hfrag[i] = *reinterpret_cast<const bf16x8*>(hp + i * 32);

        f32x4 accZ = {}, accH = {};
#pragma unroll
        for (int i = 0; i < 16; ++i) {
            accZ = __builtin_amdgcn_mfma_f32_16x16x32_bf16(aZ[i], hfrag[i], accZ, 0, 0, 0);
            accH = __builtin_amdgcn_mfma_f32_16x16x32_bf16(aH[i], hfrag[i], accH, 0, 0, 0);
        }

        if (kq == 1) {
            *reinterpret_cast<f32x4*>(&red[0][cg][lane][0]) = accZ;
            *reinterpret_cast<f32x4*>(&red[1][cg][lane][0]) = accH;
        }
        __syncthreads();

        if (kq == 0) {
            accZ += *reinterpret_cast<const f32x4*>(&red[0][cg][lane][0]);
            accH += *reinterpret_cast<const f32x4*>(&red[1][cg][lane][0]);
#pragma unroll
            for (int j = 0; j < 4; ++j) {
                float z = 1.f / (1.f + __expf(-(bzv[j] + accZ[j])));
                float hu = fmaxf(bhv[j] + accH[j], 0.f);
                hreg[j] = z * hreg[j] + (1.f - z) * hu;
            }
            // h store (bf16, contiguous u64) — must precede the release flag
            u16x4 o;
#pragma unroll
            for (int j = 0; j < 4; ++j)
                o[j] = __bfloat16_as_ushort(__float2bfloat16(hreg[j]));
            *reinterpret_cast<u64*>(hbn + (size_t)batch * H_DIM + hd0) =
                __builtin_bit_cast(u64, o);
        }

        if (t < T_DIM - 1) {
            __syncthreads();   // all waves' h stores drained into L2
            if (w == 0) {
                if (lane == 0)
                    __hip_atomic_store(&flags[(size_t)(cohort * 16 + blk) * 16],
                                       (unsigned)(t + 1),
                                       __ATOMIC_RELEASE, __HIP_MEMORY_SCOPE_AGENT);
                unsigned v;
                do {
                    v = __hip_atomic_load(&flags[(size_t)(cohort * 16 + r15) * 16],
                                          __ATOMIC_RELAXED, __HIP_MEMORY_SCOPE_AGENT);
                    if (!__any(v <= (unsigned)t)) break;
                    __builtin_amdgcn_s_sleep(1);
                } while (true);
                __builtin_amdgcn_fence(__ATOMIC_ACQUIRE, "agent");
            }
            __syncthreads();
        }

        if (kq == 0) {
            // deferred fire-and-forget stores + bn prefetch (off the flag path)
            *reinterpret_cast<f32x4*>(out + (size_t)t * BH + (size_t)batch * H_DIM + hd0) = hreg;
            if (t == T_DIM - 1)
                *reinterpret_cast<f32x4*>(out + (size_t)T_DIM * BH + (size_t)batch * H_DIM + hd0) = hreg;
            if (t + 1 < T_DIM) {
                u16x4 vz = *reinterpret_cast<const u16x4*>(
                    bnz + (size_t)(t + 1) * BH + (size_t)batch * H_DIM + hd0);
                u16x4 vh = *reinterpret_cast<const u16x4*>(
                    bnh + (size_t)(t + 1) * BH + (size_t)batch * H_DIM + hd0);
#pragma unroll
                for (int j = 0; j < 4; ++j) {
                    bzv[j] = __bfloat162float(__ushort_as_bfloat16(vz[j]));
                    bhv[j] = __bfloat162float(__ushort_as_bfloat16(vh[j]));
                }
            }
        }
    }
}

// ---------------- workspace layout (bytes) ----------------
#define OFF_XB    ((size_t)0)                     // 16 MB  bf16 x
#define OFF_WZX   ((size_t)16777216)              // 1 MB
#define OFF_WHX   ((size_t)17825792)              // 8 MB
#define OFF_UZUH  ((size_t)26214400)              // 4 MB
#define OFF_WDIAG ((size_t)30408704)              // 32 KB
#define OFF_BNZ   ((size_t)30441472)              // 32 MB
#define OFF_BNH   ((size_t)63995904)              // 32 MB
#define OFF_BAR   ((size_t)97550336)              // 4 KB flag array
#define OFF_HB0   ((size_t)98074624)              // 128 KB
#define OFF_HB1   ((size_t)98205696)              // 128 KB

extern "C" void kernel_launch(void* const* d_in, const int* in_sizes, int n_in,
                              void* d_out, int out_size, void* d_ws, size_t ws_size,
                              hipStream_t stream) {
    const float* x      = (const float*)d_in[0];
    const float* Wzx    = (const float*)d_in[1];
    const float* Whx    = (const float*)d_in[2];
    const float* Uz     = (const float*)d_in[3];
    const float* Uh     = (const float*)d_in[4];
    const float* b_unit = (const float*)d_in[5];
    const float* Wh_in  = (const float*)d_in[6];
    const float* gz     = (const float*)d_in[7];
    const float* bz     = (const float*)d_in[8];
    const float* gh     = (const float*)d_in[9];
    const float* bh     = (const float*)d_in[10];
    const float* mask   = (const float*)d_in[11];

    char* ws = (char*)d_ws;
    bf16*     xb    = (bf16*)(ws + OFF_XB);
    bf16*     wzx_b = (bf16*)(ws + OFF_WZX);
    bf16*     whx_b = (bf16*)(ws + OFF_WHX);
    bf16*     uzuh  = (bf16*)(ws + OFF_UZUH);
    float*    wdiag = (float*)(ws + OFF_WDIAG);
    bf16*     bnz   = (bf16*)(ws + OFF_BNZ);
    bf16*     bnh   = (bf16*)(ws + OFF_BNH);
    unsigned* flags = (unsigned*)(ws + OFF_BAR);
    bf16*     hb0   = (bf16*)(ws + OFF_HB0);
    bf16*     hb1   = (bf16*)(ws + OFF_HB1);

    float* out = (float*)d_out;

    // 1. convert inputs to bf16 (vectorized)
    k_cvt4<<<2048, 256, 0, stream>>>(x, (u16*)xb, T_DIM * B_DIM * I_DIM / 4);
    k_cvt4<<<512, 256, 0, stream>>>(Wzx, (u16*)wzx_b, H_DIM * I_DIM / 4);
    k_cvt4<<<2048, 256, 0, stream>>>(Whx, (u16*)whx_b, U_DIM * H_DIM * I_DIM / 4);
    k_pack_uzuh<<<2048, 256, 0, stream>>>(Uz, Uh, (u16*)uzuh);
    k_wdiag<<<(H_DIM * U_DIM + 255) / 256, 256, 0, stream>>>(Wh_in, mask, wdiag);

    // 2. fused GEMM+BN -> bnz, bnh (bf16), T-tiled x4
    {
        dim3 gz_grid(H_DIM / 64, T_DIM / 4);
        k_gemm_zx<<<gz_grid, 256, 0, stream>>>(xb, wzx_b, gz, bz, bnz);
        dim3 gs_grid(H_DIM / 16, T_DIM / 4);
        k_gemm_s<<<gs_grid, 256, 0, stream>>>(xb, whx_b, b_unit, wdiag, gh, bh, bnh);
    }

    // 3. init h = 0 and flags = 0
    hipMemsetAsync(hb0, 0, (size_t)BH * sizeof(bf16), stream);
    hipMemsetAsync(flags, 0, 4096, stream);

    // 4. persistent scan: 4 independent 16-block cohorts, fence-based exchange
    k_scan<<<64, 512, 0, stream>>>(uzuh, bnz, bnh, hb0, hb1, out, flags);
}